// Round 1
// baseline (309.261 us; speedup 1.0000x reference)
//
#include <hip/hip_runtime.h>
#include <math.h>

#define BATCH 32
#define NP 128
#define NG 64

// One block per batch sample. 128 threads: thread t owns JV column (t+1).
// JV (Jonker-Volgenant shortest augmenting path) exactly mirrors the numpy
// reference: cost computed in f32 like np.linalg.norm(f32), widened to f64;
// u/v/minv in f64; argmin tie-break = lowest column index (np.argmin).
__global__ __launch_bounds__(128) void mtl_kernel(
    const float* __restrict__ pred,    // [B,NP,3]
    const float* __restrict__ exist,   // [B,NP]
    const float* __restrict__ cnt,     // [B,1]
    const float* __restrict__ gt,      // [B,NG,3]
    const int*   __restrict__ gcnt,    // [B]
    const float* __restrict__ weight,  // [1,NP]
    float* __restrict__ out)
{
    __shared__ float  sP[NP * 3];
    __shared__ float  sG[NG * 3];
    __shared__ float  C[NG * NP];          // C[i][j] = dist(pred_j, gt_i)  (transposed cost)
    __shared__ double u[NG + 1];
    __shared__ double v[NP + 1];
    __shared__ double minv[NP + 1];
    __shared__ int    p[NP + 1];
    __shared__ int    way[NP + 1];
    __shared__ int    used[NP + 1];
    __shared__ double sval[NP];
    __shared__ int    sidx[NP];
    __shared__ int    j0_s;

    const int b   = blockIdx.x;
    const int tid = threadIdx.x;
    const int col = tid + 1;               // 1-based column this thread owns

    // ---- stage inputs ----
    for (int k = tid; k < NP * 3; k += NP) sP[k] = pred[b * NP * 3 + k];
    for (int k = tid; k < NG * 3; k += NP) sG[k] = gt[b * NG * 3 + k];
    for (int k = tid; k < NP + 1; k += NP) { v[k] = 0.0; p[k] = 0; }
    for (int k = tid; k < NG + 1; k += NP) u[k] = 0.0;
    __syncthreads();

    // ---- cost matrix, matching numpy f32 norm then cast to f64 at use ----
    {
        const float px = sP[tid * 3 + 0];
        const float py = sP[tid * 3 + 1];
        const float pz = sP[tid * 3 + 2];
        for (int i = 0; i < NG; ++i) {
            float dx = __fsub_rn(px, sG[i * 3 + 0]);
            float dy = __fsub_rn(py, sG[i * 3 + 1]);
            float dz = __fsub_rn(pz, sG[i * 3 + 2]);
            float s  = __fadd_rn(__fadd_rn(__fmul_rn(dx, dx), __fmul_rn(dy, dy)),
                                 __fmul_rn(dz, dz));
            C[i * NP + tid] = sqrtf(s);
        }
    }
    __syncthreads();

    const double INFD = 1e300;

    // ---- JV: 64 rows, sequential; inner augmenting-path search parallel over cols ----
    for (int i = 1; i <= NG; ++i) {
        if (tid == 0) { p[0] = i; j0_s = 0; used[0] = 0; minv[0] = INFD; }
        minv[col] = INFD;
        used[col] = 0;
        __syncthreads();

        while (true) {
            if (tid == 0) used[j0_s] = 1;
            __syncthreads();

            const int    j0  = j0_s;
            const int    i0  = p[j0];
            const double ui0 = u[i0];

            if (!used[col]) {
                double cur = (double)C[(i0 - 1) * NP + (col - 1)] - ui0 - v[col];
                if (cur < minv[col]) { minv[col] = cur; way[col] = j0; }
                sval[tid] = minv[col];
            } else {
                sval[tid] = INFD;
            }
            sidx[tid] = col;
            __syncthreads();

            // argmin over unused cols; tie -> lowest col index (matches np.argmin)
            for (int s = NP / 2; s > 0; s >>= 1) {
                if (tid < s) {
                    double v2 = sval[tid + s];
                    int    i2 = sidx[tid + s];
                    if (v2 < sval[tid] || (v2 == sval[tid] && i2 < sidx[tid])) {
                        sval[tid] = v2; sidx[tid] = i2;
                    }
                }
                __syncthreads();
            }
            const double delta = sval[0];
            const int    j1    = sidx[0];

            if (tid == 0) {
                if (used[0]) { u[p[0]] += delta; v[0] -= delta; }
                j0_s = j1;
            }
            if (used[col]) { u[p[col]] += delta; v[col] -= delta; }
            else           { minv[col] -= delta; }
            __syncthreads();

            if (p[j1] == 0) break;
        }

        // augment along the alternating path (serial, tiny)
        if (tid == 0) {
            int j0 = j0_s;
            while (j0) { int jn = way[j0]; p[j0] = p[jn]; j0 = jn; }
        }
        __syncthreads();
    }

    // ---- losses ----
    // p[col] != 0  =>  pred (col-1) matched to gt (p[col]-1)
    float coord = 0.0f;
    const int matched = (p[col] != 0);
    if (matched) {
        const int g = p[col] - 1;
        for (int k = 0; k < 3; ++k) {
            float d = fabsf(sP[tid * 3 + k] - sG[g * 3 + k]);
            coord += (d < 1.0f) ? 0.5f * d * d : (d - 0.5f);
        }
    }
    const float pe  = exist[b * NP + tid];
    const float lg  = fmaxf(logf(pe), -100.0f);
    const float l1m = fmaxf(log1pf(-pe), -100.0f);
    const float bce = -(matched ? lg : l1m) * weight[tid];

    sval[tid] = (double)coord;
    __syncthreads();
    for (int s = NP / 2; s > 0; s >>= 1) {
        if (tid < s) sval[tid] += sval[tid + s];
        __syncthreads();
    }
    const double coord_sum = sval[0];
    __syncthreads();

    sval[tid] = (double)bce;
    __syncthreads();
    for (int s = NP / 2; s > 0; s >>= 1) {
        if (tid < s) sval[tid] += sval[tid + s];
        __syncthreads();
    }

    if (tid == 0) {
        const double exist_sum = sval[0];
        const float  cp = cnt[b];
        const float  dc = cp - (float)gcnt[b];
        const float  sample = (float)(coord_sum / (double)(NG * 3))
                            + (float)(exist_sum / (double)NP)
                            + dc * dc;
        atomicAdd(out, sample / (float)BATCH);
    }
}

extern "C" void kernel_launch(void* const* d_in, const int* in_sizes, int n_in,
                              void* d_out, int out_size, void* d_ws, size_t ws_size,
                              hipStream_t stream) {
    const float* pred   = (const float*)d_in[0];  // [32,128,3]
    const float* exist  = (const float*)d_in[1];  // [32,128]
    const float* cnt    = (const float*)d_in[2];  // [32,1]
    const float* gt     = (const float*)d_in[3];  // [32,64,3]
    const int*   gcnt   = (const int*)d_in[4];    // [32]
    const float* weight = (const float*)d_in[5];  // [1,128]
    float* out = (float*)d_out;

    hipMemsetAsync(out, 0, sizeof(float), stream);
    mtl_kernel<<<BATCH, 128, 0, stream>>>(pred, exist, cnt, gt, gcnt, weight, out);
}

// Round 2
// 212.734 us; speedup vs baseline: 1.4537x; 1.4537x over previous
//
#include <hip/hip_runtime.h>
#include <math.h>

#define BATCH 32
#define NP 128
#define NG 64

// One wave64 per batch sample. Lane l owns:
//   - JV columns (l+1) and (l+65)  [1-based]
//   - dual u[l+1]                  [rows 1..64]
// All JV state in registers; cost matrix in LDS (read-only in hot loop);
// NO barriers in the hot loop. Argmin = shfl_xor butterfly, tie -> lowest col
// (exactly np.argmin over ascending unused cols). f64 math, same update
// order as the numpy reference => identical assignment.
__global__ __launch_bounds__(64) void mtl_kernel(
    const float* __restrict__ pred,    // [B,NP,3]
    const float* __restrict__ exist,   // [B,NP]
    const float* __restrict__ cnt,     // [B,1]
    const float* __restrict__ gt,      // [B,NG,3]
    const int*   __restrict__ gcnt,    // [B]
    const float* __restrict__ weight,  // [1,NP]
    float* __restrict__ out)
{
    __shared__ float C[NG][NP];        // C[row][col] = dist(pred_col, gt_row)
    __shared__ float sP[NP * 3];
    __shared__ float sG[NG * 3];

    const int lane = threadIdx.x;      // 0..63
    const int b    = blockIdx.x;

    // ---- stage inputs ----
    for (int k = lane; k < NP * 3; k += 64) sP[k] = pred[b * NP * 3 + k];
    for (int k = lane; k < NG * 3; k += 64) sG[k] = gt[b * NG * 3 + k];
    __syncthreads();

    // ---- cost matrix: lane computes its 2 columns over all rows ----
    {
        const float pax = sP[lane * 3 + 0], pay = sP[lane * 3 + 1], paz = sP[lane * 3 + 2];
        const float pbx = sP[(lane + 64) * 3 + 0], pby = sP[(lane + 64) * 3 + 1], pbz = sP[(lane + 64) * 3 + 2];
        for (int i = 0; i < NG; ++i) {
            const float gx = sG[i * 3 + 0], gy = sG[i * 3 + 1], gz = sG[i * 3 + 2];
            float dx = __fsub_rn(pax, gx), dy = __fsub_rn(pay, gy), dz = __fsub_rn(paz, gz);
            float sa = __fadd_rn(__fadd_rn(__fmul_rn(dx, dx), __fmul_rn(dy, dy)), __fmul_rn(dz, dz));
            dx = __fsub_rn(pbx, gx); dy = __fsub_rn(pby, gy); dz = __fsub_rn(pbz, gz);
            float sb = __fadd_rn(__fadd_rn(__fmul_rn(dx, dx), __fmul_rn(dy, dy)), __fmul_rn(dz, dz));
            C[i][lane]      = sqrtf(sa);
            C[i][lane + 64] = sqrtf(sb);
        }
    }
    __syncthreads();

    const double INFD = 1e300;

    double u_row = 0.0;                // u[lane+1]
    double v_a = 0.0, v_b = 0.0;       // v[lane+1], v[lane+65]
    int    p_a = 0,  p_b = 0;          // matched row for col (0 = free)

    for (int i = 1; i <= NG; ++i) {
        double minv_a = INFD, minv_b = INFD;
        int    way_a = 0, way_b = 0;
        bool   used_a = false, used_b = false;
        bool   row_in_path = false;
        int    j0 = 0;

        while (true) {
            // used[j0] = true; i0 = p[j0]; mark row i0 in SR path
            int i0;
            if (j0 == 0) {
                i0 = i;
            } else {
                const int src = (j0 - 1) & 63;
                const int pv  = (j0 <= 64) ? p_a : p_b;
                i0 = __shfl(pv, src);
                if (lane == src) { if (j0 <= 64) used_a = true; else used_b = true; }
            }
            if (lane == i0 - 1) row_in_path = true;
            const double ui0 = __shfl(u_row, i0 - 1);

            // scan unused cols
            const float* Crow = &C[i0 - 1][0];
            if (!used_a) {
                const double cur = (double)Crow[lane] - ui0 - v_a;
                if (cur < minv_a) { minv_a = cur; way_a = j0; }
            }
            if (!used_b) {
                const double cur = (double)Crow[lane + 64] - ui0 - v_b;
                if (cur < minv_b) { minv_b = cur; way_b = j0; }
            }

            // argmin over 128 cols, tie -> lowest col
            const double va = used_a ? INFD : minv_a;
            const double vb = used_b ? INFD : minv_b;
            double val; int cid;
            if (va <= vb) { val = va; cid = lane + 1; }
            else          { val = vb; cid = lane + 65; }
            #pragma unroll
            for (int m = 1; m < 64; m <<= 1) {
                const double ov = __shfl_xor(val, m);
                const int    oc = __shfl_xor(cid, m);
                if (ov < val || (ov == val && oc < cid)) { val = ov; cid = oc; }
            }
            const double delta = val;
            const int    j1    = cid;

            // dual updates (u[p[used]] += delta  <=>  rows in SR path)
            if (row_in_path) u_row += delta;
            if (used_a) v_a -= delta; else minv_a -= delta;
            if (used_b) v_b -= delta; else minv_b -= delta;
            j0 = j1;

            // termination: p[j1] == 0 (free column reached)
            const int pv  = (j1 <= 64) ? p_a : p_b;
            const int pj1 = __shfl(pv, (j1 - 1) & 63);
            if (pj1 == 0) break;
        }

        // augment: while j0: jn = way[j0]; p[j0] = p[jn]; j0 = jn
        int j = j0;
        while (j) {
            const int src = (j - 1) & 63;
            const int wv  = (j <= 64) ? way_a : way_b;
            const int jn  = __shfl(wv, src);
            int pnew;
            if (jn == 0) pnew = i;                      // p[0] = i
            else {
                const int pv2 = (jn <= 64) ? p_a : p_b;
                pnew = __shfl(pv2, (jn - 1) & 63);
            }
            if (lane == src) { if (j <= 64) p_a = pnew; else p_b = pnew; }
            j = jn;
        }
    }

    // ---- losses ----
    float coord = 0.0f;
    const bool m_a = (p_a != 0), m_b = (p_b != 0);
    if (m_a) {
        const int g = p_a - 1;
        for (int k = 0; k < 3; ++k) {
            const float d = fabsf(sP[lane * 3 + k] - sG[g * 3 + k]);
            coord += (d < 1.0f) ? 0.5f * d * d : (d - 0.5f);
        }
    }
    if (m_b) {
        const int g = p_b - 1;
        for (int k = 0; k < 3; ++k) {
            const float d = fabsf(sP[(lane + 64) * 3 + k] - sG[g * 3 + k]);
            coord += (d < 1.0f) ? 0.5f * d * d : (d - 0.5f);
        }
    }
    float bce = 0.0f;
    {
        const float pe  = exist[b * NP + lane];
        const float lg  = fmaxf(logf(pe), -100.0f);
        const float l1m = fmaxf(log1pf(-pe), -100.0f);
        bce += -(m_a ? lg : l1m) * weight[lane];
    }
    {
        const float pe  = exist[b * NP + lane + 64];
        const float lg  = fmaxf(logf(pe), -100.0f);
        const float l1m = fmaxf(log1pf(-pe), -100.0f);
        bce += -(m_b ? lg : l1m) * weight[lane + 64];
    }

    double cs = (double)coord;
    double es = (double)bce;
    #pragma unroll
    for (int m = 1; m < 64; m <<= 1) {
        cs += __shfl_xor(cs, m);
        es += __shfl_xor(es, m);
    }

    if (lane == 0) {
        const float cp = cnt[b];
        const float dc = cp - (float)gcnt[b];
        const float sample = (float)(cs / (double)(NG * 3))
                           + (float)(es / (double)NP)
                           + dc * dc;
        atomicAdd(out, sample / (float)BATCH);
    }
}

extern "C" void kernel_launch(void* const* d_in, const int* in_sizes, int n_in,
                              void* d_out, int out_size, void* d_ws, size_t ws_size,
                              hipStream_t stream) {
    const float* pred   = (const float*)d_in[0];  // [32,128,3]
    const float* exist  = (const float*)d_in[1];  // [32,128]
    const float* cnt    = (const float*)d_in[2];  // [32,1]
    const float* gt     = (const float*)d_in[3];  // [32,64,3]
    const int*   gcnt   = (const int*)d_in[4];    // [32]
    const float* weight = (const float*)d_in[5];  // [1,128]
    float* out = (float*)d_out;

    hipMemsetAsync(out, 0, sizeof(float), stream);
    mtl_kernel<<<BATCH, 64, 0, stream>>>(pred, exist, cnt, gt, gcnt, weight, out);
}

// Round 3
// 175.770 us; speedup vs baseline: 1.7595x; 1.2103x over previous
//
#include <hip/hip_runtime.h>
#include <math.h>

#define BATCH 32
#define NP 128
#define NG 64

__device__ __forceinline__ unsigned umin32(unsigned a, unsigned b) { return a < b ? a : b; }

// all-reduce min over each 16-lane row, pure DPP (no LDS pipe)
__device__ __forceinline__ unsigned dpp_min16(unsigned x) {
  unsigned t;
  t = (unsigned)__builtin_amdgcn_update_dpp((int)x, (int)x, 0xB1, 0xF, 0xF, false);  // quad_perm xor1
  x = umin32(x, t);
  t = (unsigned)__builtin_amdgcn_update_dpp((int)x, (int)x, 0x4E, 0xF, 0xF, false);  // quad_perm xor2
  x = umin32(x, t);
  t = (unsigned)__builtin_amdgcn_update_dpp((int)x, (int)x, 0x124, 0xF, 0xF, false); // row_ror:4
  x = umin32(x, t);
  t = (unsigned)__builtin_amdgcn_update_dpp((int)x, (int)x, 0x128, 0xF, 0xF, false); // row_ror:8
  x = umin32(x, t);
  return x;
}

// select a[k] for uniform k in [0,8) with literal indices only (keeps array in regs)
#define SEL8(a, k) ( ((k)&4) ? ( ((k)&2) ? ( ((k)&1)?(a)[7]:(a)[6] ) : ( ((k)&1)?(a)[5]:(a)[4] ) ) \
                             : ( ((k)&2) ? ( ((k)&1)?(a)[3]:(a)[2] ) : ( ((k)&1)?(a)[1]:(a)[0] ) ) )

__device__ __forceinline__ float readlane_f(float v, int l) {
  return __uint_as_float((unsigned)__builtin_amdgcn_readlane((int)__float_as_uint(v), l));
}

// One wave64 per sample. Lanes mirror lanes 0-15 (4 redundant groups); group
// lane g owns cols 8g..8g+7. JV shortest augmenting path with:
//  - packed u32 argmin key (f32+1.0 bits, low 7 bits = col id) -> 4 DPP rounds
//  - deferred dual updates (single scalar D offset per step)
//  - v_readlane (uniform lane) for p/u/way fetches and the augment chase
// No LDS-pipe ops in the per-step chain except the C-row ds_read_b128 pair.
__global__ __launch_bounds__(64) void mtl_kernel(
    const float* __restrict__ pred,    // [B,NP,3]
    const float* __restrict__ exist,   // [B,NP]
    const float* __restrict__ cnt,     // [B,1]
    const float* __restrict__ gt,      // [B,NG,3]
    const int*   __restrict__ gcnt,    // [B]
    const float* __restrict__ weight,  // [1,NP]
    float* __restrict__ out)
{
    __shared__ __align__(16) float Cld[NG * NP]; // [row][col]
    __shared__ float sP[NP * 3];
    __shared__ float sG[NG * 3];
    __shared__ int   pOut[NP];

    const int lane = threadIdx.x;      // 0..63
    const int l16  = lane & 15;
    const int b    = blockIdx.x;

    // ---- stage inputs ----
    for (int k = lane; k < NP * 3; k += 64) sP[k] = pred[b * NP * 3 + k];
    for (int k = lane; k < NG * 3; k += 64) sG[k] = gt[b * NG * 3 + k];
    __syncthreads();

    // ---- cost matrix (64 lanes, 2 cols each) ----
    {
        const float pax = sP[lane * 3 + 0], pay = sP[lane * 3 + 1], paz = sP[lane * 3 + 2];
        const float pbx = sP[(lane + 64) * 3 + 0], pby = sP[(lane + 64) * 3 + 1], pbz = sP[(lane + 64) * 3 + 2];
        for (int i = 0; i < NG; ++i) {
            const float gx = sG[i * 3 + 0], gy = sG[i * 3 + 1], gz = sG[i * 3 + 2];
            float dx = pax - gx, dy = pay - gy, dz = paz - gz;
            const float sa = dx * dx + dy * dy + dz * dz;
            dx = pbx - gx; dy = pby - gy; dz = pbz - gz;
            const float sb = dx * dx + dy * dy + dz * dz;
            Cld[i * NP + lane]      = sqrtf(sa);
            Cld[i * NP + lane + 64] = sqrtf(sb);
        }
    }
    __syncthreads();

    int   colk[8];
    float v0[8], up[8];
    int   p[8];
    #pragma unroll
    for (int k = 0; k < 8; ++k) { colk[k] = l16 * 8 + k; v0[k] = 0.0f; up[k] = 0.0f; p[k] = 0; }

    for (int i = 1; i <= NG; ++i) {
        unsigned M[8], kill[8];
        int      way[8];
        float    duse[8];
        #pragma unroll
        for (int k = 0; k < 8; ++k) { M[k] = 0xFFFFFFFFu; kill[k] = 0u; way[k] = 128; duse[k] = 0.0f; }

        int   i0  = i;
        float s1  = -1.0f;   // (u0[i0] - D) - 1.0 ; u0[i]=0, D=0 at start
        int   j0c = 128;     // current pivot col (128 = virtual root)
        int   jb  = 0;
        float Dend = 0.0f;

        for (int it = 0; it < 160; ++it) {
            // C row for pivot's matched row
            const float4* rp = (const float4*)&Cld[(i0 - 1) * NP + l16 * 8];
            const float4 ca = rp[0];
            const float4 cb = rp[1];
            const float cr[8] = {ca.x, ca.y, ca.z, ca.w, cb.x, cb.y, cb.z, cb.w};

            // per-col scan: key = bits((cur + D) + 1.0) truncated | col, OR kill
            #pragma unroll
            for (int k = 0; k < 8; ++k) {
                const float    bb = (cr[k] - v0[k]) - s1;
                const unsigned kb = ((__float_as_uint(bb) & 0xFFFFFF80u) | (unsigned)colk[k]) | kill[k];
                if (kb < M[k]) way[k] = j0c;
                M[k] = umin32(M[k], kb);
            }
            // local tree min (7 ops) then 4 DPP rounds
            unsigned m0 = umin32(M[0], M[1]);
            unsigned m1 = umin32(M[2], M[3]);
            unsigned m2 = umin32(M[4], M[5]);
            unsigned m3 = umin32(M[6], M[7]);
            m0 = umin32(m0, m1);
            m2 = umin32(m2, m3);
            const unsigned km = dpp_min16(umin32(m0, m2));

            const unsigned skey = (unsigned)__builtin_amdgcn_readfirstlane((int)km);
            const int   wc = (int)(skey & 127u);
            const float Dn = __uint_as_float(skey & 0xFFFFFF80u) - 1.0f;  // new cumulative delta
            const int   pw = __builtin_amdgcn_readlane(SEL8(p, wc & 7), wc >> 3);

            if (pw == 0 || it == 159) { jb = wc; Dend = Dn; break; }

            const float uw = readlane_f(SEL8(up, wc & 7), wc >> 3);
            // mark winner used
            #pragma unroll
            for (int k = 0; k < 8; ++k)
                if (colk[k] == wc) { kill[k] = 0xFFFFFFFFu; M[k] = 0xFFFFFFFFu; duse[k] = Dn; }
            i0  = pw;
            s1  = uw - Dn - 1.0f;
            j0c = wc;
        }

        // deferred dual updates for used cols: v -= (Dend - duse), u[p] += same
        #pragma unroll
        for (int k = 0; k < 8; ++k) {
            float diff = Dend - duse[k];
            diff = __uint_as_float(__float_as_uint(diff) & kill[k]);  // 0 if unused
            v0[k] -= diff;
            up[k] += diff;
        }

        // augment chase: p[j] <- p[way[j]], carrying the row's u value
        int j = jb;
        for (int g = 0; g < 160; ++g) {
            const int wj = __builtin_amdgcn_readlane(SEL8(way, j & 7), j >> 3);
            int parp; float paru;
            if (wj == 128) { parp = i; paru = Dend; }   // root: p[0]=i, u[i]=0+Dend
            else {
                parp = __builtin_amdgcn_readlane(SEL8(p, wj & 7), wj >> 3);
                paru = readlane_f(SEL8(up, wj & 7), wj >> 3);
            }
            #pragma unroll
            for (int k = 0; k < 8; ++k)
                if (colk[k] == j) { p[k] = parp; up[k] = paru; }
            if (wj == 128) break;
            j = wj;
        }
    }

    // publish matching (group 0 only; all groups identical)
    if (lane < 16) {
        #pragma unroll
        for (int k = 0; k < 8; ++k) pOut[colk[k]] = p[k];
    }
    __syncthreads();

    // ---- losses ----
    const int pa = pOut[lane];
    const int pb = pOut[lane + 64];
    float coord = 0.0f;
    const bool m_a = (pa != 0), m_b = (pb != 0);
    if (m_a) {
        const int g = pa - 1;
        for (int k = 0; k < 3; ++k) {
            const float d = fabsf(sP[lane * 3 + k] - sG[g * 3 + k]);
            coord += (d < 1.0f) ? 0.5f * d * d : (d - 0.5f);
        }
    }
    if (m_b) {
        const int g = pb - 1;
        for (int k = 0; k < 3; ++k) {
            const float d = fabsf(sP[(lane + 64) * 3 + k] - sG[g * 3 + k]);
            coord += (d < 1.0f) ? 0.5f * d * d : (d - 0.5f);
        }
    }
    float bce = 0.0f;
    {
        const float pe  = exist[b * NP + lane];
        const float lg  = fmaxf(logf(pe), -100.0f);
        const float l1m = fmaxf(log1pf(-pe), -100.0f);
        bce += -(m_a ? lg : l1m) * weight[lane];
    }
    {
        const float pe  = exist[b * NP + lane + 64];
        const float lg  = fmaxf(logf(pe), -100.0f);
        const float l1m = fmaxf(log1pf(-pe), -100.0f);
        bce += -(m_b ? lg : l1m) * weight[lane + 64];
    }

    double cs = (double)coord;
    double es = (double)bce;
    #pragma unroll
    for (int m = 1; m < 64; m <<= 1) {
        cs += __shfl_xor(cs, m);
        es += __shfl_xor(es, m);
    }

    if (lane == 0) {
        const float cp = cnt[b];
        const float dc = cp - (float)gcnt[b];
        const float sample = (float)(cs / (double)(NG * 3))
                           + (float)(es / (double)NP)
                           + dc * dc;
        atomicAdd(out, sample / (float)BATCH);
    }
}

extern "C" void kernel_launch(void* const* d_in, const int* in_sizes, int n_in,
                              void* d_out, int out_size, void* d_ws, size_t ws_size,
                              hipStream_t stream) {
    const float* pred   = (const float*)d_in[0];  // [32,128,3]
    const float* exist  = (const float*)d_in[1];  // [32,128]
    const float* cnt    = (const float*)d_in[2];  // [32,1]
    const float* gt     = (const float*)d_in[3];  // [32,64,3]
    const int*   gcnt   = (const int*)d_in[4];    // [32]
    const float* weight = (const float*)d_in[5];  // [1,128]
    float* out = (float*)d_out;

    hipMemsetAsync(out, 0, sizeof(float), stream);
    mtl_kernel<<<BATCH, 64, 0, stream>>>(pred, exist, cnt, gt, gcnt, weight, out);
}

// Round 4
// 121.817 us; speedup vs baseline: 2.5387x; 1.4429x over previous
//
#include <hip/hip_runtime.h>
#include <math.h>

#define BATCH 32
#define NP 128
#define NG 64

__device__ __forceinline__ unsigned umin32(unsigned a, unsigned b) { return a < b ? a : b; }

// all-reduce min over each 16-lane row, pure DPP (no LDS pipe)
__device__ __forceinline__ unsigned dpp_min16(unsigned x) {
  unsigned t;
  t = (unsigned)__builtin_amdgcn_update_dpp((int)x, (int)x, 0xB1, 0xF, 0xF, false);  // quad_perm xor1
  x = umin32(x, t);
  t = (unsigned)__builtin_amdgcn_update_dpp((int)x, (int)x, 0x4E, 0xF, 0xF, false);  // quad_perm xor2
  x = umin32(x, t);
  t = (unsigned)__builtin_amdgcn_update_dpp((int)x, (int)x, 0x124, 0xF, 0xF, false); // row_ror:4
  x = umin32(x, t);
  t = (unsigned)__builtin_amdgcn_update_dpp((int)x, (int)x, 0x128, 0xF, 0xF, false); // row_ror:8
  x = umin32(x, t);
  return x;
}

// select a[k] for uniform k in [0,8) with literal indices (keeps array in regs)
#define SEL8(a, k) ( ((k)&4) ? ( ((k)&2) ? ( ((k)&1)?(a)[7]:(a)[6] ) : ( ((k)&1)?(a)[5]:(a)[4] ) ) \
                             : ( ((k)&2) ? ( ((k)&1)?(a)[3]:(a)[2] ) : ( ((k)&1)?(a)[1]:(a)[0] ) ) )

__device__ __forceinline__ float readlane_f(float v, int l) {
  return __uint_as_float((unsigned)__builtin_amdgcn_readlane((int)__float_as_uint(v), l));
}

// One wave64 per sample. Exact LSA via LAPJV-style init + shortest augmenting
// path; optimal assignment is unique for generic costs => same matching as
// numpy's JV regardless of trajectory.
//   scan state  : lanes mirror l16=lane&15 (4 groups); lane owns cols 8*l16..+7
//   p (col->row): lane=col layout (pc_a=col lane, pc_b=col lane+64), 0=free
//   u (row dual): lane=row layout (u_row), path rows marked via enterD
__global__ __launch_bounds__(64) void mtl_kernel(
    const float* __restrict__ pred,    // [B,NP,3]
    const float* __restrict__ exist,   // [B,NP]
    const float* __restrict__ cnt,     // [B,1]
    const float* __restrict__ gt,      // [B,NG,3]
    const int*   __restrict__ gcnt,    // [B]
    const float* __restrict__ weight,  // [1,NP]
    float* __restrict__ out)
{
    __shared__ __align__(16) float Cld[NG * NP]; // [row][col]
    __shared__ float    sP[NP * 3];
    __shared__ float    sG[NG * 3];
    __shared__ unsigned aminkey[NG];
    __shared__ int      claimLds[NP];

    const int lane = threadIdx.x;      // 0..63
    const int l16  = lane & 15;
    const int grp  = lane >> 4;        // 0..3
    const int b    = blockIdx.x;
    const int cbase = l16 * 8;         // first col this lane owns (scan layout)

    // ---- stage inputs ----
    for (int k = lane; k < NP * 3; k += 64) sP[k] = pred[b * NP * 3 + k];
    for (int k = lane; k < NG * 3; k += 64) sG[k] = gt[b * NG * 3 + k];
    claimLds[lane] = 0x7FFFFFFF; claimLds[lane + 64] = 0x7FFFFFFF;
    __syncthreads();

    // ---- cost construction fused with per-row argmin ----
    // group g builds rows 16g..16g+15; lane computes its 8 cols per row.
    {
        float px[8], py[8], pz[8];
        #pragma unroll
        for (int k = 0; k < 8; ++k) {
            const int c = cbase + k;
            px[k] = sP[c * 3 + 0]; py[k] = sP[c * 3 + 1]; pz[k] = sP[c * 3 + 2];
        }
        #pragma unroll 4
        for (int t = 0; t < 16; ++t) {
            const int row = grp * 16 + t;
            const float gx = sG[row * 3 + 0], gy = sG[row * 3 + 1], gz = sG[row * 3 + 2];
            float vals[8];
            unsigned km = 0xFFFFFFFFu;
            #pragma unroll
            for (int k = 0; k < 8; ++k) {
                const float dx = px[k] - gx, dy = py[k] - gy, dz = pz[k] - gz;
                vals[k] = sqrtf(dx * dx + dy * dy + dz * dz);
                const unsigned kb = (__float_as_uint(vals[k]) & 0xFFFFFF80u) | (unsigned)(cbase + k);
                km = umin32(km, kb);
            }
            float4* wp = (float4*)&Cld[row * NP + cbase];
            wp[0] = make_float4(vals[0], vals[1], vals[2], vals[3]);
            wp[1] = make_float4(vals[4], vals[5], vals[6], vals[7]);
            km = dpp_min16(km);
            if (l16 == 0) aminkey[row] = km;
        }
    }
    __syncthreads();

    // ---- row reduction + greedy claim (lowest row wins each col) ----
    const unsigned mykey = aminkey[lane];          // lane = row
    float u_row = __uint_as_float(mykey & 0xFFFFFF80u);  // u[i] = truncated row min (feasible)
    const int amincol = (int)(mykey & 127u);
    atomicMin(&claimLds[amincol], lane);
    __syncthreads();
    const int w0 = claimLds[lane];
    const int w1 = claimLds[lane + 64];
    int pc_a = (w0 < 64) ? w0 + 1 : 0;             // col 'lane'    -> row+1 (0=free)
    int pc_b = (w1 < 64) ? w1 + 1 : 0;             // col 'lane+64' -> row+1
    const int myclaim = claimLds[amincol];         // per-lane LDS gather
    unsigned long long freemask = ~__ballot(myclaim == lane);  // rows not assigned

    float v0[8];
    #pragma unroll
    for (int k = 0; k < 8; ++k) v0[k] = 0.0f;

    // ---- SAP for each free row ----
    while (freemask) {
        const int r0 = __ffsll(freemask) - 1;      // 0-based row
        freemask &= freemask - 1;

        unsigned M[8], kill[8];
        int      way[8];
        float    duse[8];
        #pragma unroll
        for (int k = 0; k < 8; ++k) { M[k] = 0xFFFFFFFFu; kill[k] = 0u; way[k] = 255; duse[k] = 0.0f; }

        float enterD = 0.0f;
        bool  inp    = (lane == r0);
        int   i0     = r0;
        float s1     = readlane_f(u_row, r0) - 1.0f;   // u[i0] - D - 1
        int   j0c    = 255;                            // root sentinel
        float Dend   = 0.0f;
        int   jb     = 0;

        for (int it = 0; it < 192; ++it) {
            const float4* rp = (const float4*)&Cld[i0 * NP + cbase];
            const float4 ca = rp[0];
            const float4 cb = rp[1];
            const float cr[8] = {ca.x, ca.y, ca.z, ca.w, cb.x, cb.y, cb.z, cb.w};

            #pragma unroll
            for (int k = 0; k < 8; ++k) {
                const float    bb = (cr[k] - v0[k]) - s1;      // redcost + D + 1
                const unsigned kb = ((__float_as_uint(bb) & 0xFFFFFF80u) | (unsigned)(cbase + k)) | kill[k];
                if (kb < M[k]) way[k] = j0c;
                M[k] = umin32(M[k], kb);
            }
            unsigned t0 = umin32(umin32(M[0], M[1]), M[2]);
            unsigned t1 = umin32(umin32(M[3], M[4]), M[5]);
            unsigned t2 = umin32(umin32(M[6], M[7]), t0);
            const unsigned km = dpp_min16(umin32(t1, t2));

            const unsigned skey = (unsigned)__builtin_amdgcn_readfirstlane((int)km);
            const int   wc = (int)(skey & 127u);
            const float Dn = __uint_as_float(skey & 0xFFFFFF80u) - 1.0f;
            const int   psel = (wc < 64) ? pc_a : pc_b;
            const int   pw   = __builtin_amdgcn_readlane(psel, wc & 63);

            if (pw == 0 || it == 191) { jb = wc; Dend = Dn; break; }

            if (lane == pw - 1) { enterD = Dn; inp = true; }   // row enters SR path
            const float uw = readlane_f(u_row, pw - 1);
            #pragma unroll
            for (int k = 0; k < 8; ++k)
                if (cbase + k == wc) { kill[k] = 0xFFFFFFFFu; M[k] = 0xFFFFFFFFu; duse[k] = Dn; }
            s1  = uw - Dn - 1.0f;
            i0  = pw - 1;
            j0c = wc;
        }

        // deferred dual updates: used cols v -= (Dend - duse); path rows u += (Dend - enterD)
        #pragma unroll
        for (int k = 0; k < 8; ++k) {
            float diff = Dend - duse[k];
            diff = __uint_as_float(__float_as_uint(diff) & kill[k]);
            v0[k] -= diff;
        }
        u_row += inp ? (Dend - enterD) : 0.0f;

        // augment chase: p[j] <- p[way[j]]
        int j = jb;
        for (int g = 0; g < 192; ++g) {
            const int wsel = SEL8(way, j & 7);
            const int wj = __builtin_amdgcn_readlane(wsel, j >> 3);
            int parp;
            if (wj == 255) parp = r0 + 1;
            else {
                const int ps2 = (wj < 64) ? pc_a : pc_b;
                parp = __builtin_amdgcn_readlane(ps2, wj & 63);
            }
            if (j < 64) { if (lane == j)      pc_a = parp; }
            else        { if (lane == j - 64) pc_b = parp; }
            if (wj == 255) break;
            j = wj;
        }
    }

    // ---- losses (lane = col layout: pc_a/pc_b directly) ----
    const int pa = pc_a;
    const int pb = pc_b;
    float coord = 0.0f;
    const bool m_a = (pa != 0), m_b = (pb != 0);
    if (m_a) {
        const int g = pa - 1;
        for (int k = 0; k < 3; ++k) {
            const float d = fabsf(sP[lane * 3 + k] - sG[g * 3 + k]);
            coord += (d < 1.0f) ? 0.5f * d * d : (d - 0.5f);
        }
    }
    if (m_b) {
        const int g = pb - 1;
        for (int k = 0; k < 3; ++k) {
            const float d = fabsf(sP[(lane + 64) * 3 + k] - sG[g * 3 + k]);
            coord += (d < 1.0f) ? 0.5f * d * d : (d - 0.5f);
        }
    }
    float bce = 0.0f;
    {
        const float pe  = exist[b * NP + lane];
        const float lg  = fmaxf(logf(pe), -100.0f);
        const float l1m = fmaxf(log1pf(-pe), -100.0f);
        bce += -(m_a ? lg : l1m) * weight[lane];
    }
    {
        const float pe  = exist[b * NP + lane + 64];
        const float lg  = fmaxf(logf(pe), -100.0f);
        const float l1m = fmaxf(log1pf(-pe), -100.0f);
        bce += -(m_b ? lg : l1m) * weight[lane + 64];
    }

    double cs = (double)coord;
    double es = (double)bce;
    #pragma unroll
    for (int m = 1; m < 64; m <<= 1) {
        cs += __shfl_xor(cs, m);
        es += __shfl_xor(es, m);
    }

    if (lane == 0) {
        const float cp = cnt[b];
        const float dc = cp - (float)gcnt[b];
        const float sample = (float)(cs / (double)(NG * 3))
                           + (float)(es / (double)NP)
                           + dc * dc;
        atomicAdd(out, sample / (float)BATCH);
    }
}

extern "C" void kernel_launch(void* const* d_in, const int* in_sizes, int n_in,
                              void* d_out, int out_size, void* d_ws, size_t ws_size,
                              hipStream_t stream) {
    const float* pred   = (const float*)d_in[0];  // [32,128,3]
    const float* exist  = (const float*)d_in[1];  // [32,128]
    const float* cnt    = (const float*)d_in[2];  // [32,1]
    const float* gt     = (const float*)d_in[3];  // [32,64,3]
    const int*   gcnt   = (const int*)d_in[4];    // [32]
    const float* weight = (const float*)d_in[5];  // [1,128]
    float* out = (float*)d_out;

    hipMemsetAsync(out, 0, sizeof(float), stream);
    mtl_kernel<<<BATCH, 64, 0, stream>>>(pred, exist, cnt, gt, gcnt, weight, out);
}

// Round 5
// 103.912 us; speedup vs baseline: 2.9762x; 1.1723x over previous
//
#include <hip/hip_runtime.h>
#include <math.h>

#define BATCH 32
#define NP 128
#define NG 64

__device__ __forceinline__ unsigned umin32(unsigned a, unsigned b) { return a < b ? a : b; }

// min all-reduce over each 16-lane row, pure DPP
__device__ __forceinline__ unsigned dpp_min16(unsigned x) {
  unsigned t;
  t = (unsigned)__builtin_amdgcn_update_dpp((int)x, (int)x, 0xB1, 0xF, 0xF, false);  // quad_perm xor1
  x = umin32(x, t);
  t = (unsigned)__builtin_amdgcn_update_dpp((int)x, (int)x, 0x4E, 0xF, 0xF, false);  // quad_perm xor2
  x = umin32(x, t);
  t = (unsigned)__builtin_amdgcn_update_dpp((int)x, (int)x, 0x124, 0xF, 0xF, false); // row_ror:4
  x = umin32(x, t);
  t = (unsigned)__builtin_amdgcn_update_dpp((int)x, (int)x, 0x128, 0xF, 0xF, false); // row_ror:8
  x = umin32(x, t);
  return x;
}

// full-wave64 min reduce -> uniform scalar (result valid in lane 63, readlane'd)
__device__ __forceinline__ unsigned wave_min64(unsigned x) {
  x = dpp_min16(x);
  unsigned t;
  t = (unsigned)__builtin_amdgcn_update_dpp((int)x, (int)x, 0x142, 0xF, 0xF, false); // row_bcast15
  x = umin32(x, t);
  t = (unsigned)__builtin_amdgcn_update_dpp((int)x, (int)x, 0x143, 0xF, 0xF, false); // row_bcast31
  x = umin32(x, t);
  return (unsigned)__builtin_amdgcn_readlane((int)x, 63);
}

__device__ __forceinline__ float readlane_f(float v, int l) {
  return __uint_as_float((unsigned)__builtin_amdgcn_readlane((int)__float_as_uint(v), l));
}

// One wave64 per sample. Exact LSA: row-reduction + greedy claim init, then
// JV shortest augmenting path for the ~14 free rows. Lane=col layout (lane
// owns cols {lane, lane+64}) for scan/p/way; lane=row for dual u. Packed u32
// keys (truncated f32 | 7-bit col) + 6-step DPP wave argmin; deferred dual
// updates via a single running delta D. ds_read_b32 stride-1 => 2-way bank
// aliasing (free).
__global__ __launch_bounds__(64) void mtl_kernel(
    const float* __restrict__ pred,    // [B,NP,3]
    const float* __restrict__ exist,   // [B,NP]
    const float* __restrict__ cnt,     // [B,1]
    const float* __restrict__ gt,      // [B,NG,3]
    const int*   __restrict__ gcnt,    // [B]
    const float* __restrict__ weight,  // [1,NP]
    float* __restrict__ out)
{
    __shared__ __align__(16) float Cld[NG * NP]; // [row][col] row-major
    __shared__ float    sP[NP * 3];
    __shared__ float    sG[NG * 3];
    __shared__ unsigned aminkey[NG];
    __shared__ int      claimLds[NP];

    const int lane = threadIdx.x;      // 0..63
    const int l16  = lane & 15;
    const int grp  = lane >> 4;        // 0..3
    const int b    = blockIdx.x;
    const int cbase = l16 * 8;         // cols this lane builds (build phase)

    // ---- stage inputs ----
    for (int k = lane; k < NP * 3; k += 64) sP[k] = pred[b * NP * 3 + k];
    for (int k = lane; k < NG * 3; k += 64) sG[k] = gt[b * NG * 3 + k];
    claimLds[lane] = 0x7FFFFFFF; claimLds[lane + 64] = 0x7FFFFFFF;
    __syncthreads();

    // ---- cost construction fused with per-row argmin (group g: rows 16g..16g+15) ----
    {
        float px[8], py[8], pz[8];
        #pragma unroll
        for (int k = 0; k < 8; ++k) {
            const int c = cbase + k;
            px[k] = sP[c * 3 + 0]; py[k] = sP[c * 3 + 1]; pz[k] = sP[c * 3 + 2];
        }
        #pragma unroll 4
        for (int t = 0; t < 16; ++t) {
            const int row = grp * 16 + t;
            const float gx = sG[row * 3 + 0], gy = sG[row * 3 + 1], gz = sG[row * 3 + 2];
            float vals[8];
            unsigned km = 0xFFFFFFFFu;
            #pragma unroll
            for (int k = 0; k < 8; ++k) {
                const float dx = px[k] - gx, dy = py[k] - gy, dz = pz[k] - gz;
                vals[k] = sqrtf(dx * dx + dy * dy + dz * dz);
                const unsigned kb = (__float_as_uint(vals[k]) & 0xFFFFFF80u) | (unsigned)(cbase + k);
                km = umin32(km, kb);
            }
            float4* wp = (float4*)&Cld[row * NP + cbase];
            wp[0] = make_float4(vals[0], vals[1], vals[2], vals[3]);
            wp[1] = make_float4(vals[4], vals[5], vals[6], vals[7]);
            km = dpp_min16(km);
            if (l16 == 0) aminkey[row] = km;
        }
    }
    __syncthreads();

    // ---- row reduction + greedy claim (lowest row wins each col) ----
    const unsigned mykey = aminkey[lane];                 // lane = row
    float u_row = __uint_as_float(mykey & 0xFFFFFF80u);   // u[i] <= row min (feasible)
    const int amincol = (int)(mykey & 127u);
    atomicMin(&claimLds[amincol], lane);
    __syncthreads();
    const int w0 = claimLds[lane];
    const int w1 = claimLds[lane + 64];
    int pc_a = (w0 < 64) ? w0 + 1 : 0;                    // col 'lane'    -> row+1 (0=free)
    int pc_b = (w1 < 64) ? w1 + 1 : 0;                    // col 'lane+64' -> row+1
    const int myclaim = claimLds[amincol];
    unsigned long long freemask = ~__ballot(myclaim == lane);  // unassigned rows

    float v_a = 0.0f, v_b = 0.0f;                         // col duals (lane=col)

    // ---- SAP for each free row ----
    while (freemask) {
        const int r0 = __ffsll(freemask) - 1;
        freemask &= freemask - 1;

        unsigned M_a = 0xFFFFFFFFu, M_b = 0xFFFFFFFFu;
        unsigned kill_a = 0u, kill_b = 0u;
        int      way_a = 255, way_b = 255;
        float    duse_a = 0.0f, duse_b = 0.0f;

        float enterD = 0.0f;
        bool  inp    = (lane == r0);
        int   i0     = r0;
        float s1     = readlane_f(u_row, r0) - 1.0f;      // u[i0] - D - 1
        int   j0c    = 255;                               // root sentinel
        float Dend   = 0.0f;
        int   jb     = 0;

        for (int it = 0; it < 192; ++it) {
            const float c_a = Cld[i0 * NP + lane];
            const float c_b = Cld[i0 * NP + lane + 64];

            // key = bits(redcost + D + 1) truncated | col, OR kill
            const float    bb_a = (c_a - v_a) - s1;
            const float    bb_b = (c_b - v_b) - s1;
            const unsigned kb_a = ((__float_as_uint(bb_a) & 0xFFFFFF80u) | (unsigned)lane) | kill_a;
            const unsigned kb_b = ((__float_as_uint(bb_b) & 0xFFFFFF80u) | (unsigned)(lane + 64)) | kill_b;
            if (kb_a < M_a) way_a = j0c;
            if (kb_b < M_b) way_b = j0c;
            M_a = umin32(M_a, kb_a);
            M_b = umin32(M_b, kb_b);

            const unsigned skey = wave_min64(umin32(M_a, M_b));
            const int   wc = (int)(skey & 127u);
            const float Dn = __uint_as_float(skey & 0xFFFFFF80u) - 1.0f;

            const int pw1 = __builtin_amdgcn_readlane(pc_a, wc & 63);
            const int pw2 = __builtin_amdgcn_readlane(pc_b, wc & 63);
            const int pw  = (wc < 64) ? pw1 : pw2;

            if (pw == 0 || it == 191) { jb = wc; Dend = Dn; break; }

            if (lane == pw - 1) { enterD = Dn; inp = true; }   // row enters SR path
            if (wc == lane)      { kill_a = 0xFFFFFFFFu; M_a = 0xFFFFFFFFu; duse_a = Dn; }
            if (wc == lane + 64) { kill_b = 0xFFFFFFFFu; M_b = 0xFFFFFFFFu; duse_b = Dn; }

            const float uw = readlane_f(u_row, pw - 1);
            s1  = uw - Dn - 1.0f;
            i0  = pw - 1;
            j0c = wc;
        }

        // deferred dual updates: used cols v -= (Dend - duse); path rows u += (Dend - enterD)
        float da = Dend - duse_a, db = Dend - duse_b;
        v_a -= __uint_as_float(__float_as_uint(da) & kill_a);
        v_b -= __uint_as_float(__float_as_uint(db) & kill_b);
        u_row += inp ? (Dend - enterD) : 0.0f;

        // augment chase: p[j] <- p[way[j]]
        int j = jb;
        for (int g = 0; g < 192; ++g) {
            const int wj1 = __builtin_amdgcn_readlane(way_a, j & 63);
            const int wj2 = __builtin_amdgcn_readlane(way_b, j & 63);
            const int wj  = (j < 64) ? wj1 : wj2;
            int parp;
            if (wj == 255) parp = r0 + 1;
            else {
                const int q1 = __builtin_amdgcn_readlane(pc_a, wj & 63);
                const int q2 = __builtin_amdgcn_readlane(pc_b, wj & 63);
                parp = (wj < 64) ? q1 : q2;
            }
            if (j < 64) { if (lane == j)      pc_a = parp; }
            else        { if (lane == j - 64) pc_b = parp; }
            if (wj == 255) break;
            j = wj;
        }
    }

    // ---- losses (lane = col layout: pc_a/pc_b directly) ----
    const int pa = pc_a;
    const int pb = pc_b;
    float coord = 0.0f;
    const bool m_a = (pa != 0), m_b = (pb != 0);
    if (m_a) {
        const int g = pa - 1;
        for (int k = 0; k < 3; ++k) {
            const float d = fabsf(sP[lane * 3 + k] - sG[g * 3 + k]);
            coord += (d < 1.0f) ? 0.5f * d * d : (d - 0.5f);
        }
    }
    if (m_b) {
        const int g = pb - 1;
        for (int k = 0; k < 3; ++k) {
            const float d = fabsf(sP[(lane + 64) * 3 + k] - sG[g * 3 + k]);
            coord += (d < 1.0f) ? 0.5f * d * d : (d - 0.5f);
        }
    }
    float bce = 0.0f;
    {
        const float pe  = exist[b * NP + lane];
        const float lg  = fmaxf(logf(pe), -100.0f);
        const float l1m = fmaxf(log1pf(-pe), -100.0f);
        bce += -(m_a ? lg : l1m) * weight[lane];
    }
    {
        const float pe  = exist[b * NP + lane + 64];
        const float lg  = fmaxf(logf(pe), -100.0f);
        const float l1m = fmaxf(log1pf(-pe), -100.0f);
        bce += -(m_b ? lg : l1m) * weight[lane + 64];
    }

    double cs = (double)coord;
    double es = (double)bce;
    #pragma unroll
    for (int m = 1; m < 64; m <<= 1) {
        cs += __shfl_xor(cs, m);
        es += __shfl_xor(es, m);
    }

    if (lane == 0) {
        const float cp = cnt[b];
        const float dc = cp - (float)gcnt[b];
        const float sample = (float)(cs / (double)(NG * 3))
                           + (float)(es / (double)NP)
                           + dc * dc;
        atomicAdd(out, sample / (float)BATCH);
    }
}

extern "C" void kernel_launch(void* const* d_in, const int* in_sizes, int n_in,
                              void* d_out, int out_size, void* d_ws, size_t ws_size,
                              hipStream_t stream) {
    const float* pred   = (const float*)d_in[0];  // [32,128,3]
    const float* exist  = (const float*)d_in[1];  // [32,128]
    const float* cnt    = (const float*)d_in[2];  // [32,1]
    const float* gt     = (const float*)d_in[3];  // [32,64,3]
    const int*   gcnt   = (const int*)d_in[4];    // [32]
    const float* weight = (const float*)d_in[5];  // [1,128]
    float* out = (float*)d_out;

    hipMemsetAsync(out, 0, sizeof(float), stream);
    mtl_kernel<<<BATCH, 64, 0, stream>>>(pred, exist, cnt, gt, gcnt, weight, out);
}